// Round 18
// baseline (615.094 us; speedup 1.0000x reference)
//
#include <hip/hip_runtime.h>
#include <hip/hip_bf16.h>
#include <hip/hip_fp16.h>

// ResidualGNN: 2x GCNConv(128->128, relu) + FC(128->3, tanh), N=100000, E=1.6M, fp32.
// R17: feature-slice partitioning. H/A1/H2 stored slice-major [8][N][16 halves];
//      gather blocks pick slice = blockIdx&7 so each XCD's L2 (4MB) holds one
//      3.2MB slice (round-robin blockIdx->XCD mapping). Gather reads 32B/edge
//      (8 lanes x dword) + shfl_xor(8,16,32) cross-group reduce. FC head emits
//      per-slice partials; finalize kernel sums + tanh.

#define NODE_F 128

typedef __attribute__((ext_vector_type(8))) short bf16x8;
typedef __attribute__((ext_vector_type(8))) unsigned short u16x8;
typedef __attribute__((ext_vector_type(4))) float f32x4;

__device__ inline unsigned short bf16_rn(float x) {
    unsigned u = __builtin_bit_cast(unsigned, x);
    unsigned r = (u + 0x7fffu + ((u >> 16) & 1u)) >> 16;
    return (unsigned short)r;
}
__device__ inline float bf16_to_f(unsigned short h) {
    unsigned u = (unsigned)h << 16;
    return __builtin_bit_cast(float, u);
}

// ---- W -> bf16 hi/lo, transposed to [n][k] ------------------------------

__global__ __launch_bounds__(256) void wconv_kernel(const float* __restrict__ W1,
                                                    const float* __restrict__ W2,
                                                    unsigned short* __restrict__ WhiT,
                                                    unsigned short* __restrict__ WloT)
{
    const float* W = blockIdx.x ? W2 : W1;
    unsigned short* hiT = WhiT + blockIdx.x * 128 * 128;
    unsigned short* loT = WloT + blockIdx.x * 128 * 128;
    int tid = threadIdx.x;
    for (int i = tid; i < 128 * 128; i += 256) {
        int k = i >> 7, n = i & 127;
        float x = W[i];
        unsigned short hi = bf16_rn(x);
        float lo = x - bf16_to_f(hi);
        hiT[n * 128 + k] = hi;
        loT[n * 128 + k] = bf16_rn(lo);
    }
}

// ---- scan ---------------------------------------------------------------

__global__ __launch_bounds__(256) void scan_block_kernel(
    const int* __restrict__ degE, int* __restrict__ rsA,
    int* __restrict__ bsum, int N)
{
    __shared__ int s[256];
    const int tid = threadIdx.x;
    const int idx = blockIdx.x * 1024 + tid * 4;
    int v0 = (idx + 0 < N) ? degE[idx + 0] : 0;
    int v1 = (idx + 1 < N) ? degE[idx + 1] : 0;
    int v2 = (idx + 2 < N) ? degE[idx + 2] : 0;
    int v3 = (idx + 3 < N) ? degE[idx + 3] : 0;
    int t = v0 + v1 + v2 + v3;
    s[tid] = t;
    __syncthreads();
    #pragma unroll
    for (int off = 1; off < 256; off <<= 1) {
        int x = (tid >= off) ? s[tid - off] : 0;
        __syncthreads();
        s[tid] += x;
        __syncthreads();
    }
    int excl = s[tid] - t;
    if (idx + 0 < N) rsA[idx + 0] = excl;
    if (idx + 1 < N) rsA[idx + 1] = excl + v0;
    if (idx + 2 < N) rsA[idx + 2] = excl + v0 + v1;
    if (idx + 3 < N) rsA[idx + 3] = excl + v0 + v1 + v2;
    if (tid == 255) bsum[blockIdx.x] = s[255];
}

__global__ __launch_bounds__(1024) void scan_tops_kernel(int* __restrict__ bsum, int nb) {
    __shared__ int s[1024];
    const int tid = threadIdx.x;
    int v = (tid < nb) ? bsum[tid] : 0;
    s[tid] = v;
    __syncthreads();
    #pragma unroll
    for (int off = 1; off < 1024; off <<= 1) {
        int x = (tid >= off) ? s[tid - off] : 0;
        __syncthreads();
        s[tid] += x;
        __syncthreads();
    }
    if (tid < nb) bsum[tid] = s[tid] - v;
}

// ---- finish || fill -----------------------------------------------------

__global__ __launch_bounds__(256) void finish_fill_kernel(
    const int* __restrict__ src, const int* __restrict__ dst,
    const unsigned short* __restrict__ rank,
    const int* __restrict__ rsA, const int* __restrict__ bsum,
    int* __restrict__ rsB, float* __restrict__ dinv,
    const int* __restrict__ degE, int* __restrict__ csr_src,
    int E, int N, int fill_blocks)
{
    if ((int)blockIdx.x < fill_blocks) {
        int e = blockIdx.x * 256 + threadIdx.x;
        if (e < E) {
            int d = dst[e];
            csr_src[rsA[d] + bsum[d >> 10] + (int)rank[e]] = src[e];
        }
    } else {
        int i = (blockIdx.x - fill_blocks) * 256 + threadIdx.x;
        if (i < N) {
            int rs = rsA[i] + bsum[i >> 10];
            rsB[i] = rs;
            dinv[i] = rsqrtf((float)degE[i] + 1.0f);
            if (i == N - 1) rsB[N] = rs + degE[i];
        }
    }
}

// ---- GEMM compute core: slice-major epilogue ----------------------------
// Hout layout: [slice=f>>4][node][f&15] halves; slice stride = N*16.

template<bool SCALE_OUT>
__device__ __forceinline__ void gemm_compute(
    const unsigned short* __restrict__ WhiT, const unsigned short* __restrict__ WloT,
    const float* __restrict__ dinv, __half* __restrict__ Hout, int N, int rbase,
    unsigned short* xhi, unsigned short* xlo)
{
    const int tid  = threadIdx.x;
    const int lane = tid & 63;
    const int w    = tid >> 6;

    bf16x8 bhi[2][4], blo[2][4];
    {
        int n0   = w * 32 + (lane & 15);
        int koct = (lane >> 4) * 8;
        #pragma unroll
        for (int nt = 0; nt < 2; ++nt) {
            #pragma unroll
            for (int kk = 0; kk < 4; ++kk) {
                size_t o = (size_t)(n0 + nt * 16) * 128 + kk * 32 + koct;
                bhi[nt][kk] = *reinterpret_cast<const bf16x8*>(WhiT + o);
                blo[nt][kk] = *reinterpret_cast<const bf16x8*>(WloT + o);
            }
        }
    }

    f32x4 acc[4][2];
    #pragma unroll
    for (int m = 0; m < 4; ++m)
        #pragma unroll
        for (int nt = 0; nt < 2; ++nt)
            acc[m][nt] = (f32x4){0.f, 0.f, 0.f, 0.f};

    #pragma unroll
    for (int kk = 0; kk < 4; ++kk) {
        #pragma unroll
        for (int m = 0; m < 4; ++m) {
            int row  = m * 16 + (lane & 15);
            int koff = kk * 64 + (lane >> 4) * 16;
            int byte = row * 256 + (koff ^ ((row & 7) << 4));
            bf16x8 ahi = *reinterpret_cast<const bf16x8*>(reinterpret_cast<char*>(xhi) + byte);
            bf16x8 alo = *reinterpret_cast<const bf16x8*>(reinterpret_cast<char*>(xlo) + byte);
            #pragma unroll
            for (int nt = 0; nt < 2; ++nt) {
                acc[m][nt] = __builtin_amdgcn_mfma_f32_16x16x32_bf16(ahi, bhi[nt][kk], acc[m][nt], 0, 0, 0);
                acc[m][nt] = __builtin_amdgcn_mfma_f32_16x16x32_bf16(ahi, blo[nt][kk], acc[m][nt], 0, 0, 0);
                acc[m][nt] = __builtin_amdgcn_mfma_f32_16x16x32_bf16(alo, bhi[nt][kk], acc[m][nt], 0, 0, 0);
            }
        }
    }

    #pragma unroll
    for (int m = 0; m < 4; ++m) {
        int row = rbase + m * 16 + (lane >> 4) * 4;
        int col = w * 32 + (lane & 15);
        #pragma unroll
        for (int nt = 0; nt < 2; ++nt) {
            int f = col + nt * 16;
            __half* outp = Hout + (size_t)(f >> 4) * ((size_t)N * 16) + (f & 15);
            #pragma unroll
            for (int r = 0; r < 4; ++r) {
                if (row + r < N) {
                    float v = acc[m][nt][r];
                    if (SCALE_OUT) v *= dinv[row + r];
                    outp[(size_t)(row + r) * 16] = __float2half(v);
                }
            }
        }
    }
}

// ---- gemm1 body: fp32 input, convert+split staging ----------------------

__device__ __forceinline__ void gemm1_body(
    const float* __restrict__ Xf,
    const unsigned short* __restrict__ WhiT, const unsigned short* __restrict__ WloT,
    __half* __restrict__ Hout, int N, int bid,
    unsigned short* xhi, unsigned short* xlo)
{
    const int tid   = threadIdx.x;
    const int rbase = bid * 64;

    #pragma unroll
    for (int it = 0; it < 8; ++it) {
        int f   = it * 256 + tid;
        int row = f >> 5;
        int k4  = f & 31;
        float4 v = make_float4(0.f, 0.f, 0.f, 0.f);
        if (rbase + row < N)
            v = *reinterpret_cast<const float4*>(Xf + (size_t)(rbase + row) * NODE_F + k4 * 4);
        float xs[4] = {v.x, v.y, v.z, v.w};
        ushort4 h4, l4;
        unsigned short* hp = &h4.x;
        unsigned short* lp = &l4.x;
        #pragma unroll
        for (int j = 0; j < 4; ++j) {
            unsigned short hi = bf16_rn(xs[j]);
            hp[j] = hi;
            lp[j] = bf16_rn(xs[j] - bf16_to_f(hi));
        }
        int byte = row * 256 + ((k4 * 8) ^ ((row & 7) << 4));
        *reinterpret_cast<ushort4*>(reinterpret_cast<char*>(xhi) + byte) = h4;
        *reinterpret_cast<ushort4*>(reinterpret_cast<char*>(xlo) + byte) = l4;
    }
    __syncthreads();
    gemm_compute<false>(WhiT, WloT, nullptr, Hout, N, rbase, xhi, xlo);
}

// ---- gemm1 + deg_rank as 1:4 modulo-interleaved block roles -------------

__global__ __launch_bounds__(256) void gemm1deg_kernel(
    const int* __restrict__ dst, int* __restrict__ degE,
    unsigned short* __restrict__ rank, int E,
    int edge_blocks, int gemm_blocks,
    const float* __restrict__ X, const unsigned short* __restrict__ WhiT,
    const unsigned short* __restrict__ WloT, __half* __restrict__ H, int N)
{
    __shared__ unsigned short xhi[64 * 128];
    __shared__ unsigned short xlo[64 * 128];
    int q = blockIdx.x / 5, r = blockIdx.x % 5;
    if (r == 4) {
        int stride = edge_blocks * 256;
        for (int e = q * 256 + threadIdx.x; e < E; e += stride)
            rank[e] = (unsigned short)atomicAdd(&degE[dst[e]], 1);
    } else {
        int gid = q * 4 + r;
        if (gid < gemm_blocks)
            gemm1_body(X, WhiT, WloT, H, N, gid, xhi, xlo);
    }
}

// ---- sliced gather core: 8 lane-groups x 8 lanes; 32B/edge from one slice

template<bool EDGE_SCALE>
__device__ __forceinline__ void gather_slice(
    const __half* __restrict__ Hsl, const int* __restrict__ csr_src,
    const int* __restrict__ row_start, const float* __restrict__ dinv,
    int node, int g, int f2, float2& a)
{
    const unsigned* Hu = reinterpret_cast<const unsigned*>(Hsl);
    a.x = 0.f; a.y = 0.f;
    if (g == 0) {
        float ds = EDGE_SCALE ? dinv[node] : 1.0f;
        float2 h = __half22float2(__builtin_bit_cast(__half2, Hu[(size_t)node * 8 + f2]));
        a.x += h.x * ds; a.y += h.y * ds;
    }
    int i   = row_start[node];
    int end = row_start[node + 1];
    for (; i + 15 < end; i += 16) {
        int s0 = csr_src[i + g];
        int s1 = csr_src[i + 8 + g];
        float d0 = EDGE_SCALE ? dinv[s0] : 1.0f;
        float d1 = EDGE_SCALE ? dinv[s1] : 1.0f;
        unsigned v0 = Hu[(size_t)s0 * 8 + f2];
        unsigned v1 = Hu[(size_t)s1 * 8 + f2];
        float2 h0 = __half22float2(__builtin_bit_cast(__half2, v0));
        float2 h1 = __half22float2(__builtin_bit_cast(__half2, v1));
        a.x += h0.x * d0 + h1.x * d1;
        a.y += h0.y * d0 + h1.y * d1;
    }
    for (; i < end; i += 8) {
        if (i + g < end) {
            int s = csr_src[i + g];
            float ds = EDGE_SCALE ? dinv[s] : 1.0f;
            float2 h = __half22float2(__builtin_bit_cast(__half2, Hu[(size_t)s * 8 + f2]));
            a.x += h.x * ds; a.y += h.y * ds;
        }
    }
    // reduce across the 8 groups (same f2)
    a.x += __shfl_xor(a.x, 8);  a.y += __shfl_xor(a.y, 8);
    a.x += __shfl_xor(a.x, 16); a.y += __shfl_xor(a.y, 16);
    a.x += __shfl_xor(a.x, 32); a.y += __shfl_xor(a.y, 32);
}

#define NPW 4   // nodes per wave (serial)

// ---- gather1s: A1[slice][node] = relu(b + dd*(sum dinv[s] H[s])) fp16 ---

__global__ __launch_bounds__(256) void gather1s_kernel(
    const __half* __restrict__ H, const int* __restrict__ csr_src,
    const int* __restrict__ row_start, const float* __restrict__ dinv,
    const float* __restrict__ b1, __half* __restrict__ A1, int N)
{
    const int slice = blockIdx.x & 7;
    const int wave  = threadIdx.x >> 6;
    const int lane  = threadIdx.x & 63;
    const int g = lane >> 3, f2 = lane & 7;
    const __half* Hsl = H  + (size_t)slice * ((size_t)N * 16);
    unsigned*     Asl = reinterpret_cast<unsigned*>(A1) + (size_t)slice * ((size_t)N * 8);
    const int base = ((blockIdx.x >> 3) * 4 + wave) * NPW;

    for (int t = 0; t < NPW; ++t) {
        int node = base + t;
        if (node >= N) return;
        float2 a;
        gather_slice<true>(Hsl, csr_src, row_start, dinv, node, g, f2, a);
        if (g == 0) {
            float dd = dinv[node];
            int f = slice * 16 + f2 * 2;
            float r0 = fmaxf(b1[f]     + dd * a.x, 0.f);
            float r1 = fmaxf(b1[f + 1] + dd * a.y, 0.f);
            __half2 o = __float22half2_rn(make_float2(r0, r1));
            Asl[(size_t)node * 8 + f2] = __builtin_bit_cast(unsigned, o);
        }
    }
}

// ---- gemm2: slice-major fp16 input, split to bf16 hi/lo during staging --

__global__ __launch_bounds__(256) void gemm2_kernel(
    const __half* __restrict__ A1,
    const unsigned short* __restrict__ WhiT, const unsigned short* __restrict__ WloT,
    const float* __restrict__ dinv, __half* __restrict__ Hs, int N)
{
    __shared__ unsigned short xhi[64 * 128];
    __shared__ unsigned short xlo[64 * 128];
    const int tid   = threadIdx.x;
    const int rbase = blockIdx.x * 64;

    #pragma unroll
    for (int it = 0; it < 4; ++it) {
        int idx = it * 256 + tid;          // 8-half units; 1024 total
        int row = idx >> 4;
        int k8  = idx & 15;
        u16x8 h = {0, 0, 0, 0, 0, 0, 0, 0};
        u16x8 l = {0, 0, 0, 0, 0, 0, 0, 0};
        if (rbase + row < N) {
            int slice = k8 >> 1;
            int j0    = (k8 & 1) * 8;
            u16x8 v = *reinterpret_cast<const u16x8*>(
                reinterpret_cast<const unsigned short*>(A1) +
                (size_t)slice * ((size_t)N * 16) + (size_t)(rbase + row) * 16 + j0);
            #pragma unroll
            for (int j = 0; j < 8; ++j) {
                float f = __half2float(__builtin_bit_cast(__half, (unsigned short)v[j]));
                unsigned short hi = bf16_rn(f);
                h[j] = hi;
                l[j] = bf16_rn(f - bf16_to_f(hi));
            }
        }
        int byte = row * 256 + ((k8 * 16) ^ ((row & 7) << 4));
        *reinterpret_cast<u16x8*>(reinterpret_cast<char*>(xhi) + byte) = h;
        *reinterpret_cast<u16x8*>(reinterpret_cast<char*>(xlo) + byte) = l;
    }
    __syncthreads();
    gemm_compute<true>(WhiT, WloT, dinv, Hs, N, rbase, xhi, xlo);
}

// ---- gather2fcs: per-slice FC partials ----------------------------------

__global__ __launch_bounds__(256) void gather2fcs_kernel(
    const __half* __restrict__ Hs, const int* __restrict__ csr_src,
    const int* __restrict__ row_start, const float* __restrict__ dinv,
    const float* __restrict__ b2, const float* __restrict__ Wfc,
    float* __restrict__ outPart, int N)
{
    const int slice = blockIdx.x & 7;
    const int wave  = threadIdx.x >> 6;
    const int lane  = threadIdx.x & 63;
    const int g = lane >> 3, f2 = lane & 7;
    const __half* Hsl = Hs + (size_t)slice * ((size_t)N * 16);
    const int base = ((blockIdx.x >> 3) * 4 + wave) * NPW;

    for (int t = 0; t < NPW; ++t) {
        int node = base + t;
        if (node >= N) return;
        float2 a;
        gather_slice<false>(Hsl, csr_src, row_start, dinv, node, g, f2, a);
        if (g == 0) {
            float dd = dinv[node];
            int f = slice * 16 + f2 * 2;
            float r0 = fmaxf(b2[f]     + dd * a.x, 0.f);
            float r1 = fmaxf(b2[f + 1] + dd * a.y, 0.f);
            float p0 = r0 * Wfc[f * 3 + 0] + r1 * Wfc[(f + 1) * 3 + 0];
            float p1 = r0 * Wfc[f * 3 + 1] + r1 * Wfc[(f + 1) * 3 + 1];
            float p2 = r0 * Wfc[f * 3 + 2] + r1 * Wfc[(f + 1) * 3 + 2];
            #pragma unroll
            for (int off = 1; off < 8; off <<= 1) {
                p0 += __shfl_xor(p0, off);
                p1 += __shfl_xor(p1, off);
                p2 += __shfl_xor(p2, off);
            }
            if (f2 == 0) {
                float* op = outPart + ((size_t)slice * N + node) * 3;
                op[0] = p0; op[1] = p1; op[2] = p2;
            }
        }
    }
}

// ---- finalize: out = tanh(sum_slices partial + bfc) ---------------------

__global__ __launch_bounds__(256) void fc_finalize_kernel(
    const float* __restrict__ outPart, const float* __restrict__ bfc,
    float* __restrict__ out, int N)
{
    int i = blockIdx.x * 256 + threadIdx.x;   // over N*3
    if (i >= N * 3) return;
    int c = i % 3;
    float s = bfc[c];
    #pragma unroll
    for (int sl = 0; sl < 8; ++sl)
        s += outPart[(size_t)sl * ((size_t)N * 3) + i];
    out[i] = tanhf(s);
}

extern "C" void kernel_launch(void* const* d_in, const int* in_sizes, int n_in,
                              void* d_out, int out_size, void* d_ws, size_t ws_size,
                              hipStream_t stream)
{
    const float* x    = (const float*)d_in[0];
    const int*   edge = (const int*)d_in[1];
    const float* W1   = (const float*)d_in[2];
    const float* b1   = (const float*)d_in[3];
    const float* W2   = (const float*)d_in[4];
    const float* b2   = (const float*)d_in[5];
    const float* Wfc  = (const float*)d_in[6];
    const float* bfc  = (const float*)d_in[7];
    float* out = (float*)d_out;

    const int N = in_sizes[0] / NODE_F;
    const int E = in_sizes[1] / 2;
    const int* src = edge;
    const int* dst = edge + E;

    char* ws = (char*)d_ws;
    size_t off = 0;
    auto alloc = [&](size_t bytes) {
        void* p = ws + off;
        off += (bytes + 511) & ~511ull;
        return p;
    };
    const int nblk = (N + 1023) / 1024;
    float* dinv      = (float*)alloc((size_t)N * 4);
    int*   degE      = (int*)  alloc((size_t)N * 4);
    unsigned short* rank = (unsigned short*)alloc((size_t)E * 2);
    int*   rsA       = (int*)  alloc((size_t)N * 4);
    int*   rsB       = (int*)  alloc((size_t)(N + 1) * 4);
    int*   bsum      = (int*)  alloc((size_t)nblk * 4);
    int*   csr_src   = (int*)  alloc((size_t)E * 4);
    unsigned short* WhiT = (unsigned short*)alloc(2 * 128 * 128 * 2);
    unsigned short* WloT = (unsigned short*)alloc(2 * 128 * 128 * 2);
    __half* H        = (__half*)alloc((size_t)N * NODE_F * 2);
    __half* A1       = (__half*)alloc((size_t)N * NODE_F * 2);
    __half* H2       = (__half*)alloc((size_t)N * NODE_F * 2);
    float*  outPart  = (float*)alloc((size_t)8 * N * 3 * 4);
    (void)ws_size; (void)n_in; (void)out_size;

    const int B = 256;
    const int gemm_grid   = (N + 63) / 64;
    const int fill_blocks = (E + B - 1) / B;
    const int fin_blocks  = (N + B - 1) / B;
    const int node_chunks = (N + 4 * NPW - 1) / (4 * NPW);
    const int gatherS_grid = node_chunks * 8;

    // 1:4 interleave for gemm1deg
    const int edge_blocks  = (gemm_grid + 3) / 4;
    const int total_blocks = gemm_grid + edge_blocks + 4;

    wconv_kernel<<<2, B, 0, stream>>>(W1, W2, WhiT, WloT);
    hipMemsetAsync(degE, 0, (size_t)N * 4, stream);

    // gemm1 (unscaled H, slice-major) with deg_rank as interleaved block roles
    gemm1deg_kernel<<<total_blocks, B, 0, stream>>>(
        dst, degE, rank, E, edge_blocks, gemm_grid, x, WhiT, WloT, H, N);

    scan_block_kernel<<<nblk, B, 0, stream>>>(degE, rsA, bsum, N);
    scan_tops_kernel<<<1, 1024, 0, stream>>>(bsum, nblk);

    // [fill csr || finalize row_start + dinv]
    finish_fill_kernel<<<fill_blocks + fin_blocks, B, 0, stream>>>(
        src, dst, rank, rsA, bsum, rsB, dinv, degE, csr_src, E, N, fill_blocks);

    // layer-1 aggregate, slice-partitioned (XCD-L2-resident slices)
    gather1s_kernel<<<gatherS_grid, B, 0, stream>>>(H, csr_src, rsB, dinv, b1, A1, N);

    // layer-2 GEMM (slice-major in/out, scaled epilogue)
    gemm2_kernel<<<gemm_grid, B, 0, stream>>>(A1, WhiT + 128 * 128, WloT + 128 * 128,
                                              dinv, H2, N);

    // layer-2 aggregate + per-slice FC partials
    gather2fcs_kernel<<<gatherS_grid, B, 0, stream>>>(H2, csr_src, rsB, dinv, b2,
                                                      Wfc, outPart, N);

    // finalize: sum slices + bias + tanh
    fc_finalize_kernel<<<(N * 3 + B - 1) / B, B, 0, stream>>>(outPart, bfc, out, N);
}

// Round 19
// 301.724 us; speedup vs baseline: 2.0386x; 2.0386x over previous
//
#include <hip/hip_runtime.h>
#include <hip/hip_bf16.h>
#include <hip/hip_fp16.h>

// ResidualGNN: 2x GCNConv(128->128, relu) + FC(128->3, tanh), N=100000, E=1.6M, fp32.
// R18: revert slice partitioning (FETCH 188->79MB but 3x slower: 32B requests are
//      below transaction granularity -> latency-bound; 256B-row gather at ~2.5TB/s
//      is the efficient operating point). Locked best config (R11/R17, 302us).

#define NODE_F 128

typedef __attribute__((ext_vector_type(8))) short bf16x8;
typedef __attribute__((ext_vector_type(8))) unsigned short u16x8;
typedef __attribute__((ext_vector_type(4))) float f32x4;

__device__ inline unsigned short bf16_rn(float x) {
    unsigned u = __builtin_bit_cast(unsigned, x);
    unsigned r = (u + 0x7fffu + ((u >> 16) & 1u)) >> 16;
    return (unsigned short)r;
}
__device__ inline float bf16_to_f(unsigned short h) {
    unsigned u = (unsigned)h << 16;
    return __builtin_bit_cast(float, u);
}
__device__ inline void acc8_h(float a[8], uint4 v, float s) {
    unsigned vv[4] = {v.x, v.y, v.z, v.w};
    #pragma unroll
    for (int j = 0; j < 4; ++j) {
        float2 f = __half22float2(__builtin_bit_cast(__half2, vv[j]));
        a[2 * j]     += f.x * s;
        a[2 * j + 1] += f.y * s;
    }
}

// ---- W -> bf16 hi/lo, transposed to [n][k] ------------------------------

__global__ __launch_bounds__(256) void wconv_kernel(const float* __restrict__ W1,
                                                    const float* __restrict__ W2,
                                                    unsigned short* __restrict__ WhiT,
                                                    unsigned short* __restrict__ WloT)
{
    const float* W = blockIdx.x ? W2 : W1;
    unsigned short* hiT = WhiT + blockIdx.x * 128 * 128;
    unsigned short* loT = WloT + blockIdx.x * 128 * 128;
    int tid = threadIdx.x;
    for (int i = tid; i < 128 * 128; i += 256) {
        int k = i >> 7, n = i & 127;
        float x = W[i];
        unsigned short hi = bf16_rn(x);
        float lo = x - bf16_to_f(hi);
        hiT[n * 128 + k] = hi;
        loT[n * 128 + k] = bf16_rn(lo);
    }
}

// ---- scan ---------------------------------------------------------------

__global__ __launch_bounds__(256) void scan_block_kernel(
    const int* __restrict__ degE, int* __restrict__ rsA,
    int* __restrict__ bsum, int N)
{
    __shared__ int s[256];
    const int tid = threadIdx.x;
    const int idx = blockIdx.x * 1024 + tid * 4;
    int v0 = (idx + 0 < N) ? degE[idx + 0] : 0;
    int v1 = (idx + 1 < N) ? degE[idx + 1] : 0;
    int v2 = (idx + 2 < N) ? degE[idx + 2] : 0;
    int v3 = (idx + 3 < N) ? degE[idx + 3] : 0;
    int t = v0 + v1 + v2 + v3;
    s[tid] = t;
    __syncthreads();
    #pragma unroll
    for (int off = 1; off < 256; off <<= 1) {
        int x = (tid >= off) ? s[tid - off] : 0;
        __syncthreads();
        s[tid] += x;
        __syncthreads();
    }
    int excl = s[tid] - t;
    if (idx + 0 < N) rsA[idx + 0] = excl;
    if (idx + 1 < N) rsA[idx + 1] = excl + v0;
    if (idx + 2 < N) rsA[idx + 2] = excl + v0 + v1;
    if (idx + 3 < N) rsA[idx + 3] = excl + v0 + v1 + v2;
    if (tid == 255) bsum[blockIdx.x] = s[255];
}

__global__ __launch_bounds__(1024) void scan_tops_kernel(int* __restrict__ bsum, int nb) {
    __shared__ int s[1024];
    const int tid = threadIdx.x;
    int v = (tid < nb) ? bsum[tid] : 0;
    s[tid] = v;
    __syncthreads();
    #pragma unroll
    for (int off = 1; off < 1024; off <<= 1) {
        int x = (tid >= off) ? s[tid - off] : 0;
        __syncthreads();
        s[tid] += x;
        __syncthreads();
    }
    if (tid < nb) bsum[tid] = s[tid] - v;
}

// ---- finish || fill (both read rsA+bsum; no cross-dependency) -----------

__global__ __launch_bounds__(256) void finish_fill_kernel(
    const int* __restrict__ src, const int* __restrict__ dst,
    const unsigned short* __restrict__ rank,
    const int* __restrict__ rsA, const int* __restrict__ bsum,
    int* __restrict__ rsB, float* __restrict__ dinv,
    const int* __restrict__ degE, int* __restrict__ csr_src,
    int E, int N, int fill_blocks)
{
    if ((int)blockIdx.x < fill_blocks) {
        int e = blockIdx.x * 256 + threadIdx.x;
        if (e < E) {
            int d = dst[e];
            csr_src[rsA[d] + bsum[d >> 10] + (int)rank[e]] = src[e];
        }
    } else {
        int i = (blockIdx.x - fill_blocks) * 256 + threadIdx.x;
        if (i < N) {
            int rs = rsA[i] + bsum[i >> 10];
            rsB[i] = rs;
            dinv[i] = rsqrtf((float)degE[i] + 1.0f);
            if (i == N - 1) rsB[N] = rs + degE[i];
        }
    }
}

// ---- GEMM compute core: B-frag preload + MFMA + epilogue ----------------

template<bool SCALE_OUT>
__device__ __forceinline__ void gemm_compute(
    const unsigned short* __restrict__ WhiT, const unsigned short* __restrict__ WloT,
    const float* __restrict__ dinv, __half* __restrict__ Hout, int N, int rbase,
    unsigned short* xhi, unsigned short* xlo)
{
    const int tid  = threadIdx.x;
    const int lane = tid & 63;
    const int w    = tid >> 6;

    bf16x8 bhi[2][4], blo[2][4];
    {
        int n0   = w * 32 + (lane & 15);
        int koct = (lane >> 4) * 8;
        #pragma unroll
        for (int nt = 0; nt < 2; ++nt) {
            #pragma unroll
            for (int kk = 0; kk < 4; ++kk) {
                size_t o = (size_t)(n0 + nt * 16) * 128 + kk * 32 + koct;
                bhi[nt][kk] = *reinterpret_cast<const bf16x8*>(WhiT + o);
                blo[nt][kk] = *reinterpret_cast<const bf16x8*>(WloT + o);
            }
        }
    }

    f32x4 acc[4][2];
    #pragma unroll
    for (int m = 0; m < 4; ++m)
        #pragma unroll
        for (int nt = 0; nt < 2; ++nt)
            acc[m][nt] = (f32x4){0.f, 0.f, 0.f, 0.f};

    #pragma unroll
    for (int kk = 0; kk < 4; ++kk) {
        #pragma unroll
        for (int m = 0; m < 4; ++m) {
            int row  = m * 16 + (lane & 15);
            int koff = kk * 64 + (lane >> 4) * 16;
            int byte = row * 256 + (koff ^ ((row & 7) << 4));
            bf16x8 ahi = *reinterpret_cast<const bf16x8*>(reinterpret_cast<char*>(xhi) + byte);
            bf16x8 alo = *reinterpret_cast<const bf16x8*>(reinterpret_cast<char*>(xlo) + byte);
            #pragma unroll
            for (int nt = 0; nt < 2; ++nt) {
                acc[m][nt] = __builtin_amdgcn_mfma_f32_16x16x32_bf16(ahi, bhi[nt][kk], acc[m][nt], 0, 0, 0);
                acc[m][nt] = __builtin_amdgcn_mfma_f32_16x16x32_bf16(ahi, blo[nt][kk], acc[m][nt], 0, 0, 0);
                acc[m][nt] = __builtin_amdgcn_mfma_f32_16x16x32_bf16(alo, bhi[nt][kk], acc[m][nt], 0, 0, 0);
            }
        }
    }

    #pragma unroll
    for (int m = 0; m < 4; ++m) {
        int row = rbase + m * 16 + (lane >> 4) * 4;
        int col = w * 32 + (lane & 15);
        #pragma unroll
        for (int nt = 0; nt < 2; ++nt) {
            #pragma unroll
            for (int r = 0; r < 4; ++r) {
                if (row + r < N) {
                    float v = acc[m][nt][r];
                    if (SCALE_OUT) v *= dinv[row + r];
                    Hout[(size_t)(row + r) * NODE_F + col + nt * 16] = __float2half(v);
                }
            }
        }
    }
}

// ---- gemm1 body: fp32 input, convert+split staging ----------------------

__device__ __forceinline__ void gemm1_body(
    const float* __restrict__ Xf,
    const unsigned short* __restrict__ WhiT, const unsigned short* __restrict__ WloT,
    __half* __restrict__ Hout, int N, int bid,
    unsigned short* xhi, unsigned short* xlo)
{
    const int tid   = threadIdx.x;
    const int rbase = bid * 64;

    #pragma unroll
    for (int it = 0; it < 8; ++it) {
        int f   = it * 256 + tid;
        int row = f >> 5;
        int k4  = f & 31;
        float4 v = make_float4(0.f, 0.f, 0.f, 0.f);
        if (rbase + row < N)
            v = *reinterpret_cast<const float4*>(Xf + (size_t)(rbase + row) * NODE_F + k4 * 4);
        float xs[4] = {v.x, v.y, v.z, v.w};
        ushort4 h4, l4;
        unsigned short* hp = &h4.x;
        unsigned short* lp = &l4.x;
        #pragma unroll
        for (int j = 0; j < 4; ++j) {
            unsigned short hi = bf16_rn(xs[j]);
            hp[j] = hi;
            lp[j] = bf16_rn(xs[j] - bf16_to_f(hi));
        }
        int byte = row * 256 + ((k4 * 8) ^ ((row & 7) << 4));
        *reinterpret_cast<ushort4*>(reinterpret_cast<char*>(xhi) + byte) = h4;
        *reinterpret_cast<ushort4*>(reinterpret_cast<char*>(xlo) + byte) = l4;
    }
    __syncthreads();
    gemm_compute<false>(WhiT, WloT, nullptr, Hout, N, rbase, xhi, xlo);
}

// ---- gemm1 + deg_rank as 1:4 modulo-interleaved block roles -------------

__global__ __launch_bounds__(256) void gemm1deg_kernel(
    const int* __restrict__ dst, int* __restrict__ degE,
    unsigned short* __restrict__ rank, int E,
    int edge_blocks, int gemm_blocks,
    const float* __restrict__ X, const unsigned short* __restrict__ WhiT,
    const unsigned short* __restrict__ WloT, __half* __restrict__ H, int N)
{
    __shared__ unsigned short xhi[64 * 128];
    __shared__ unsigned short xlo[64 * 128];
    int q = blockIdx.x / 5, r = blockIdx.x % 5;
    if (r == 4) {
        int stride = edge_blocks * 256;
        for (int e = q * 256 + threadIdx.x; e < E; e += stride)
            rank[e] = (unsigned short)atomicAdd(&degE[dst[e]], 1);
    } else {
        int gid = q * 4 + r;
        if (gid < gemm_blocks)
            gemm1_body(X, WhiT, WloT, H, N, gid, xhi, xlo);
    }
}

// ---- gather core: quarter-wave per edge, 16B/lane; optional per-edge dinv

template<bool EDGE_SCALE>
__device__ __forceinline__ void gather_core(
    const __half* __restrict__ Hs, const int* __restrict__ csr_src,
    const int* __restrict__ row_start, const float* __restrict__ dinv,
    int node, int ql, int qi, float a[8])
{
    const char* Hb = reinterpret_cast<const char*>(Hs);
    #pragma unroll
    for (int j = 0; j < 8; ++j) a[j] = 0.f;
    if (qi == 0) {
        float ds = EDGE_SCALE ? dinv[node] : 1.0f;
        acc8_h(a, *reinterpret_cast<const uint4*>(Hb + ((size_t)node * 256 + ql * 16)), ds);
    }

    int i   = row_start[node];
    int end = row_start[node + 1];
    for (; i + 7 < end; i += 8) {
        int s0 = csr_src[i + qi];
        int s1 = csr_src[i + 4 + qi];
        float d0 = EDGE_SCALE ? dinv[s0] : 1.0f;
        float d1 = EDGE_SCALE ? dinv[s1] : 1.0f;
        uint4 v0 = *reinterpret_cast<const uint4*>(Hb + ((size_t)s0 * 256 + ql * 16));
        uint4 v1 = *reinterpret_cast<const uint4*>(Hb + ((size_t)s1 * 256 + ql * 16));
        acc8_h(a, v0, d0);
        acc8_h(a, v1, d1);
    }
    for (; i < end; i += 4) {
        if (i + qi < end) {
            int s = csr_src[i + qi];
            float ds = EDGE_SCALE ? dinv[s] : 1.0f;
            acc8_h(a, *reinterpret_cast<const uint4*>(Hb + ((size_t)s * 256 + ql * 16)), ds);
        }
    }
    #pragma unroll
    for (int j = 0; j < 8; ++j) {
        a[j] += __shfl_xor(a[j], 32);
        a[j] += __shfl_xor(a[j], 16);
    }
}

// ---- gather1: A1 = relu(b + dinv[d]*(sum dinv[s] H[s])) as fp16 ---------

__global__ __launch_bounds__(256) void gather1_kernel(
    const __half* __restrict__ H, const int* __restrict__ csr_src,
    const int* __restrict__ row_start, const float* __restrict__ dinv,
    const float* __restrict__ b, __half* __restrict__ A1, int N)
{
    int node = (blockIdx.x * blockDim.x + threadIdx.x) >> 6;
    int lane = threadIdx.x & 63;
    int ql = lane & 15, qi = lane >> 4;
    if (node >= N) return;

    float a[8];
    gather_core<true>(H, csr_src, row_start, dinv, node, ql, qi, a);

    if (qi == 0) {
        const float dd = dinv[node];
        u16x8 o;
        #pragma unroll
        for (int j = 0; j < 8; ++j) {
            float r = fmaxf(b[ql * 8 + j] + dd * a[j], 0.f);
            o[j] = __builtin_bit_cast(unsigned short, __float2half(r));
        }
        *reinterpret_cast<u16x8*>(reinterpret_cast<char*>(A1) + ((size_t)node * 256 + ql * 16)) = o;
    }
}

// ---- gemm2: fp16 input, split fp16->bf16 hi/lo during staging -----------

__global__ __launch_bounds__(256) void gemm2_kernel(
    const __half* __restrict__ A1,
    const unsigned short* __restrict__ WhiT, const unsigned short* __restrict__ WloT,
    const float* __restrict__ dinv, __half* __restrict__ Hs, int N)
{
    __shared__ unsigned short xhi[64 * 128];
    __shared__ unsigned short xlo[64 * 128];
    const int tid   = threadIdx.x;
    const int rbase = blockIdx.x * 64;

    #pragma unroll
    for (int it = 0; it < 4; ++it) {
        int idx = it * 256 + tid;          // 8-half units; 1024 total
        int row = idx >> 4;
        int k8  = idx & 15;
        u16x8 h = {0, 0, 0, 0, 0, 0, 0, 0};
        u16x8 l = {0, 0, 0, 0, 0, 0, 0, 0};
        if (rbase + row < N) {
            u16x8 v = *reinterpret_cast<const u16x8*>(
                reinterpret_cast<const char*>(A1) + ((size_t)(rbase + row) * 256 + k8 * 16));
            #pragma unroll
            for (int j = 0; j < 8; ++j) {
                float f = __half2float(__builtin_bit_cast(__half, (unsigned short)v[j]));
                unsigned short hi = bf16_rn(f);
                h[j] = hi;
                l[j] = bf16_rn(f - bf16_to_f(hi));
            }
        }
        int byte = row * 256 + ((k8 * 16) ^ ((row & 7) << 4));
        *reinterpret_cast<u16x8*>(reinterpret_cast<char*>(xhi) + byte) = h;
        *reinterpret_cast<u16x8*>(reinterpret_cast<char*>(xlo) + byte) = l;
    }
    __syncthreads();
    gemm_compute<true>(WhiT, WloT, dinv, Hs, N, rbase, xhi, xlo);
}

// ---- gather2 + FC (pre-scaled Hs): out = tanh(relu(b + dd*sum) @ Wfc + bfc)

__global__ __launch_bounds__(256) void gather2fc_kernel(
    const __half* __restrict__ Hs, const int* __restrict__ csr_src,
    const int* __restrict__ row_start, const float* __restrict__ dinv,
    const float* __restrict__ b, const float* __restrict__ Wfc,
    const float* __restrict__ bfc, float* __restrict__ out, int N)
{
    int node = (blockIdx.x * blockDim.x + threadIdx.x) >> 6;
    int lane = threadIdx.x & 63;
    int ql = lane & 15, qi = lane >> 4;
    if (node >= N) return;

    float a[8];
    gather_core<false>(Hs, csr_src, row_start, dinv, node, ql, qi, a);

    const float dd = dinv[node];
    float p0 = 0.f, p1 = 0.f, p2 = 0.f;
    #pragma unroll
    for (int j = 0; j < 8; ++j) {
        float r = fmaxf(b[ql * 8 + j] + dd * a[j], 0.f);
        const float* wr = Wfc + (size_t)(ql * 8 + j) * 3;
        p0 += r * wr[0]; p1 += r * wr[1]; p2 += r * wr[2];
    }
    #pragma unroll
    for (int off = 8; off > 0; off >>= 1) {
        p0 += __shfl_down(p0, off);
        p1 += __shfl_down(p1, off);
        p2 += __shfl_down(p2, off);
    }
    if (lane == 0) {
        out[(size_t)node * 3 + 0] = tanhf(p0 + bfc[0]);
        out[(size_t)node * 3 + 1] = tanhf(p1 + bfc[1]);
        out[(size_t)node * 3 + 2] = tanhf(p2 + bfc[2]);
    }
}

extern "C" void kernel_launch(void* const* d_in, const int* in_sizes, int n_in,
                              void* d_out, int out_size, void* d_ws, size_t ws_size,
                              hipStream_t stream)
{
    const float* x    = (const float*)d_in[0];
    const int*   edge = (const int*)d_in[1];
    const float* W1   = (const float*)d_in[2];
    const float* b1   = (const float*)d_in[3];
    const float* W2   = (const float*)d_in[4];
    const float* b2   = (const float*)d_in[5];
    const float* Wfc  = (const float*)d_in[6];
    const float* bfc  = (const float*)d_in[7];
    float* out = (float*)d_out;

    const int N = in_sizes[0] / NODE_F;
    const int E = in_sizes[1] / 2;
    const int* src = edge;
    const int* dst = edge + E;

    char* ws = (char*)d_ws;
    size_t off = 0;
    auto alloc = [&](size_t bytes) {
        void* p = ws + off;
        off += (bytes + 511) & ~511ull;
        return p;
    };
    const int nblk = (N + 1023) / 1024;
    float* dinv      = (float*)alloc((size_t)N * 4);
    int*   degE      = (int*)  alloc((size_t)N * 4);
    unsigned short* rank = (unsigned short*)alloc((size_t)E * 2);
    int*   rsA       = (int*)  alloc((size_t)N * 4);
    int*   rsB       = (int*)  alloc((size_t)(N + 1) * 4);
    int*   bsum      = (int*)  alloc((size_t)nblk * 4);
    int*   csr_src   = (int*)  alloc((size_t)E * 4);
    unsigned short* WhiT = (unsigned short*)alloc(2 * 128 * 128 * 2);
    unsigned short* WloT = (unsigned short*)alloc(2 * 128 * 128 * 2);
    __half* H        = (__half*)alloc((size_t)N * NODE_F * 2);
    __half* A1       = (__half*)alloc((size_t)N * NODE_F * 2);
    __half* H2       = (__half*)alloc((size_t)N * NODE_F * 2);
    (void)ws_size; (void)n_in; (void)out_size;

    const int B = 256;
    const int gemm_grid   = (N + 63) / 64;
    const int gather_grid = (N + 3) / 4;
    const int fill_blocks = (E + B - 1) / B;
    const int fin_blocks  = (N + B - 1) / B;

    // 1:4 interleave for gemm1deg
    const int edge_blocks  = (gemm_grid + 3) / 4;
    const int total_blocks = gemm_grid + edge_blocks + 4;

    wconv_kernel<<<2, B, 0, stream>>>(W1, W2, WhiT, WloT);
    hipMemsetAsync(degE, 0, (size_t)N * 4, stream);

    // gemm1 (unscaled H) with deg_rank as interleaved block roles
    gemm1deg_kernel<<<total_blocks, B, 0, stream>>>(
        dst, degE, rank, E, edge_blocks, gemm_grid, x, WhiT, WloT, H, N);

    scan_block_kernel<<<nblk, B, 0, stream>>>(degE, rsA, bsum, N);
    scan_tops_kernel<<<1, 1024, 0, stream>>>(bsum, nblk);

    // [fill csr || finalize row_start + dinv]
    finish_fill_kernel<<<fill_blocks + fin_blocks, B, 0, stream>>>(
        src, dst, rank, rsA, bsum, rsB, dinv, degE, csr_src, E, N, fill_blocks);

    // layer-1 aggregate (per-edge dinv) -> relu -> fp16
    gather1_kernel<<<gather_grid, B, 0, stream>>>(H, csr_src, rsB, dinv, b1, A1, N);

    // layer-2 GEMM (fp16 input, in-register split, scaled epilogue)
    gemm2_kernel<<<gemm_grid, B, 0, stream>>>(A1, WhiT + 128 * 128, WloT + 128 * 128,
                                              dinv, H2, N);

    // layer-2 aggregate + FC head
    gather2fc_kernel<<<gather_grid, B, 0, stream>>>(H2, csr_src, rsB, dinv, b2,
                                                    Wfc, bfc, out, N);
}